// Round 3
// baseline (152.276 us; speedup 1.0000x reference)
//
#include <hip/hip_runtime.h>
#include <math.h>

#define N_SAMP 16384
#define DIN 128
#define FDIM 128
#define BINS 32
#define NEDGE 33
#define CELLS (FDIM * NEDGE)   // 4224
#define H1 1024
#define H2 512
#define NC 10

#define K1_BLOCKS 1024
#define K1_ROWS 16             // 1024*16 = 16384 samples
#define K1_THREADS 512
#define XS_STRIDE 132          // 128+4: 16B-aligned rows, breaks pow2 bank stride

#define K2_GROUPS 32           // 32 groups x 32 partials = 1024
#define K3_BLOCKS 256

#define EXP_3_125 22.7598950f  // e^3.125

__device__ __forceinline__ float sig_from_t(float t) {
    // sigma = 1/(1+t), t = e^{-z}; t->0 => 1, t->inf => 0 (correct saturation)
    return __builtin_amdgcn_rcpf(1.f + t);
}
__device__ __forceinline__ float lrelu(float x) { return x > 0.f ? x : 0.01f * x; }

template <int NE>
__device__ __forceinline__ void sig_chain(float z0neg, float* locE) {
    // z0neg = c0 - 100*s ; t_j = e^{z0neg + 3.125 j}, monotone in j.
    float tt = __expf(z0neg);
    #pragma unroll
    for (int j = 0; j < NE; ++j) {
        locE[j] += sig_from_t(tt);
        tt *= EXP_3_125;
    }
}

// ---------------------------------------------------------------------------
// K1: fused  s = sigmoid(x@Wf + bf)  +  per-block edge sums
//     E_part[blk][f*33+e] = sum_rows sigma(100*s - 3.125*e)
// 1024 blocks x 512 thr x 16 rows -> 4 blocks/CU, 32 waves/CU.
// ---------------------------------------------------------------------------
__global__ __launch_bounds__(K1_THREADS, 8) void k1_feat_hist(
    const float* __restrict__ x, const float* __restrict__ Wf,
    const float* __restrict__ bf, float* __restrict__ E_part)
{
    __shared__ float xs[K1_ROWS * XS_STRIDE];
    const int t = threadIdx.x;
    const int blk = blockIdx.x;
    const int row0 = blk * K1_ROWS;

    // ---- load x tile: 16 rows x 128 cols, one float4 per thread ----
    {
        const int r = t >> 5, c4 = (t & 31) << 2;
        *(float4*)&xs[r * XS_STRIDE + c4] =
            *(const float4*)(x + (size_t)(row0 + r) * DIN + c4);
    }
    __syncthreads();

    // ---- GEMM: thread tile = 1 row x 4 feats ----
    const int tc = t & 31, tr = t >> 5;   // tr = row 0..15
    const int f0 = tc * 4;

    float4 acc = {0, 0, 0, 0};
    #pragma unroll 4
    for (int d = 0; d < DIN; d += 4) {
        const float4 xa = *(const float4*)&xs[tr * XS_STRIDE + d];
        const float* wp = Wf + d * FDIM + f0;
        const float4 w0 = *(const float4*)(wp);
        const float4 w1 = *(const float4*)(wp + FDIM);
        const float4 w2 = *(const float4*)(wp + 2 * FDIM);
        const float4 w3 = *(const float4*)(wp + 3 * FDIM);
        acc.x = fmaf(xa.x, w0.x, acc.x); acc.y = fmaf(xa.x, w0.y, acc.y);
        acc.z = fmaf(xa.x, w0.z, acc.z); acc.w = fmaf(xa.x, w0.w, acc.w);
        acc.x = fmaf(xa.y, w1.x, acc.x); acc.y = fmaf(xa.y, w1.y, acc.y);
        acc.z = fmaf(xa.y, w1.z, acc.z); acc.w = fmaf(xa.y, w1.w, acc.w);
        acc.x = fmaf(xa.z, w2.x, acc.x); acc.y = fmaf(xa.z, w2.y, acc.y);
        acc.z = fmaf(xa.z, w2.z, acc.z); acc.w = fmaf(xa.z, w2.w, acc.w);
        acc.x = fmaf(xa.w, w3.x, acc.x); acc.y = fmaf(xa.w, w3.y, acc.y);
        acc.z = fmaf(xa.w, w3.z, acc.z); acc.w = fmaf(xa.w, w3.w, acc.w);
    }

    const float4 bv = *(const float4*)(bf + f0);
    float4 sv;
    sv.x = sig_from_t(__expf(-(acc.x + bv.x)));
    sv.y = sig_from_t(__expf(-(acc.y + bv.y)));
    sv.z = sig_from_t(__expf(-(acc.z + bv.z)));
    sv.w = sig_from_t(__expf(-(acc.w + bv.w)));

    __syncthreads();   // all GEMM reads of x done before overwriting with s
    *(float4*)&xs[tr * XS_STRIDE + f0] = sv;
    __syncthreads();

    // ---- edge sums. thread = (feat, edge-group); eg sizes 9,8,8,8. ----
    // Chain is always-correct (exp flush/inf -> exact saturated sigma);
    // __all() wave-uniform skips avoid issuing it when the whole wave is
    // saturated (common: s concentrates in [0.39,0.61]).
    const int feat = t & 127;
    const int eg = t >> 7;                          // wave-uniform (2 waves/eg)
    const int estart = (eg == 0) ? 0 : eg * 8 + 1;  // 0,9,17,25
    const int ne = (eg == 0) ? 9 : 8;
    const float c0 = 3.125f * (float)estart;
    const float cLast = 3.125f * (float)(estart + ne - 1);

    float locE[9];
    #pragma unroll
    for (int j = 0; j < 9; ++j) locE[j] = 0.f;
    float cnt = 0.f;   // rows where all edges saturated high

    for (int r = 0; r < K1_ROWS; ++r) {
        const float z100 = 100.f * xs[r * XS_STRIDE + feat];
        if (__all(z100 - c0 <= -15.f)) {
            // whole wave: all edges sigma ~= 0
        } else if (__all(z100 - cLast >= 15.f)) {
            cnt += 1.f;               // all edges sigma ~= 1
        } else {
            if (eg == 0) sig_chain<9>(c0 - z100, locE);
            else         sig_chain<8>(c0 - z100, locE);
        }
    }

    float* dst = E_part + (size_t)blk * CELLS + feat * NEDGE + estart;
    for (int j = 0; j < ne; ++j) dst[j] = locE[j] + cnt;
}

// ---------------------------------------------------------------------------
// K2: coalesced reduce E_part[1024][4224] -> E32[32][4224]
// grid (17, 32): x covers cells in chunks of 256, y = partial-group.
// For fixed p, a wave reads 64 consecutive cells: perfectly coalesced.
// ---------------------------------------------------------------------------
__global__ __launch_bounds__(256) void k2_reduce(
    const float* __restrict__ E_part, float* __restrict__ E32)
{
    const int cell = blockIdx.x * 256 + threadIdx.x;
    if (cell >= CELLS) return;
    const int g = blockIdx.y;
    const float* p = E_part + (size_t)g * 32 * CELLS + cell;
    float a0 = 0, a1 = 0, a2 = 0, a3 = 0;
    #pragma unroll
    for (int q = 0; q < 32; q += 4) {
        a0 += p[(size_t)(q + 0) * CELLS];
        a1 += p[(size_t)(q + 1) * CELLS];
        a2 += p[(size_t)(q + 2) * CELLS];
        a3 += p[(size_t)(q + 3) * CELLS];
    }
    E32[g * CELLS + cell] = (a0 + a1) + (a2 + a3);
}

// ---------------------------------------------------------------------------
// K3: final 32-way reduce of 17 edge cells (L2-resident E32), telescope to
//     16 hist values, then h1_part[b][:] = hist-chunk @ 16 W1 rows.
//     W1 register-prefetched first to hide HBM latency behind the reduce.
// ---------------------------------------------------------------------------
__global__ __launch_bounds__(256) void k3_h1(
    const float* __restrict__ E32, const float* __restrict__ W1,
    float* __restrict__ h1_part)
{
    const int b = blockIdx.x, t = threadIdx.x;
    const int f = b >> 1, bin0 = (b & 1) * 16;
    const int c0 = f * NEDGE + bin0;

    float4 w[16];
    #pragma unroll
    for (int k = 0; k < 16; ++k)
        w[k] = *(const float4*)(W1 + (size_t)(b * 16 + k) * H1 + t * 4);

    __shared__ float hl[17];
    if (t < 17) {
        const float* p = E32 + c0 + t;
        float a0 = 0, a1 = 0, a2 = 0, a3 = 0;
        #pragma unroll
        for (int g = 0; g < 32; g += 4) {
            a0 += p[(size_t)(g + 0) * CELLS];
            a1 += p[(size_t)(g + 1) * CELLS];
            a2 += p[(size_t)(g + 2) * CELLS];
            a3 += p[(size_t)(g + 3) * CELLS];
        }
        hl[t] = (a0 + a1) + (a2 + a3);
    }
    __syncthreads();

    float4 acc = {0, 0, 0, 0};
    #pragma unroll
    for (int k = 0; k < 16; ++k) {
        const float h = (hl[k] - hl[k + 1]) * (1.f / (float)N_SAMP);
        acc.x = fmaf(h, w[k].x, acc.x);
        acc.y = fmaf(h, w[k].y, acc.y);
        acc.z = fmaf(h, w[k].z, acc.z);
        acc.w = fmaf(h, w[k].w, acc.w);
    }
    *(float4*)(h1_part + (size_t)b * H1 + t * 4) = acc;
}

// ---------------------------------------------------------------------------
// K5: finalize 8 h1 entries (256-way reduce + b1 + leaky), then
//     h2_part[b][:] = h1-chunk @ 8 W2 rows (register-prefetched).
// ---------------------------------------------------------------------------
__global__ __launch_bounds__(128) void k5_h2(
    const float* __restrict__ h1_part, const float* __restrict__ b1,
    const float* __restrict__ W2, float* __restrict__ h2_part)
{
    const int b = blockIdx.x, t = threadIdx.x;   // 128 blocks x 128 thr

    float4 w[8];
    #pragma unroll
    for (int k = 0; k < 8; ++k)
        w[k] = *(const float4*)(W2 + (size_t)(b * 8 + k) * H2 + t * 4);

    __shared__ float hred[8 * 16];
    __shared__ float hv[8];
    const int col = t & 7, q = t >> 3;   // 16 partial-groups of 16
    {
        const float* p0 = h1_part + (size_t)(q * 16) * H1 + b * 8 + col;
        float a0 = 0, a1 = 0, a2 = 0, a3 = 0;
        #pragma unroll
        for (int p = 0; p < 16; p += 4) {
            a0 += p0[(size_t)(p + 0) * H1];
            a1 += p0[(size_t)(p + 1) * H1];
            a2 += p0[(size_t)(p + 2) * H1];
            a3 += p0[(size_t)(p + 3) * H1];
        }
        hred[col * 16 + q] = (a0 + a1) + (a2 + a3);
    }
    __syncthreads();
    if (t < 8) {
        float s = 0.f;
        #pragma unroll
        for (int q2 = 0; q2 < 16; ++q2) s += hred[t * 16 + q2];
        hv[t] = lrelu(s + b1[b * 8 + t]);
    }
    __syncthreads();

    float4 acc = {0, 0, 0, 0};
    #pragma unroll
    for (int k = 0; k < 8; ++k) {
        const float h = hv[k];
        acc.x = fmaf(h, w[k].x, acc.x);
        acc.y = fmaf(h, w[k].y, acc.y);
        acc.z = fmaf(h, w[k].z, acc.z);
        acc.w = fmaf(h, w[k].w, acc.w);
    }
    *(float4*)(h2_part + (size_t)b * H2 + t * 4) = acc;
}

// ---------------------------------------------------------------------------
// K6: finalize h2 (128-way reduce + b2 + leaky), logits = h2@W3 + b3,
//     softmax -> out[10]. Single block of 512.
// ---------------------------------------------------------------------------
__global__ __launch_bounds__(512) void k6_final(
    const float* __restrict__ h2_part, const float* __restrict__ b2,
    const float* __restrict__ W3, const float* __restrict__ b3,
    float* __restrict__ out)
{
    const int t = threadIdx.x;
    float a0 = 0, a1 = 0, a2 = 0, a3 = 0;
    #pragma unroll 8
    for (int p = 0; p < 128; p += 4) {
        a0 += h2_part[(size_t)(p + 0) * H2 + t];
        a1 += h2_part[(size_t)(p + 1) * H2 + t];
        a2 += h2_part[(size_t)(p + 2) * H2 + t];
        a3 += h2_part[(size_t)(p + 3) * H2 + t];
    }
    const float h2v = lrelu(((a0 + a1) + (a2 + a3)) + b2[t]);

    float lc[NC];
    #pragma unroll
    for (int c = 0; c < NC; ++c) lc[c] = h2v * W3[t * NC + c];
    #pragma unroll
    for (int off = 32; off >= 1; off >>= 1) {
        #pragma unroll
        for (int c = 0; c < NC; ++c) lc[c] += __shfl_down(lc[c], off, 64);
    }

    __shared__ float wsum[8][NC];
    if ((t & 63) == 0) {
        #pragma unroll
        for (int c = 0; c < NC; ++c) wsum[t >> 6][c] = lc[c];
    }
    __syncthreads();

    if (t == 0) {
        float logits[NC];
        float m = -1e30f;
        #pragma unroll
        for (int c = 0; c < NC; ++c) {
            float v = b3[c];
            for (int ww = 0; ww < 8; ++ww) v += wsum[ww][c];
            logits[c] = v;
            m = fmaxf(m, v);
        }
        float ssum = 0.f;
        #pragma unroll
        for (int c = 0; c < NC; ++c) { logits[c] = __expf(logits[c] - m); ssum += logits[c]; }
        const float inv = 1.f / ssum;
        #pragma unroll
        for (int c = 0; c < NC; ++c) out[c] = logits[c] * inv;
    }
}

extern "C" void kernel_launch(void* const* d_in, const int* in_sizes, int n_in,
                              void* d_out, int out_size, void* d_ws, size_t ws_size,
                              hipStream_t stream)
{
    const float* x  = (const float*)d_in[0];
    const float* Wf = (const float*)d_in[1];
    const float* bf = (const float*)d_in[2];
    const float* W1 = (const float*)d_in[3];
    const float* b1 = (const float*)d_in[4];
    const float* W2 = (const float*)d_in[5];
    const float* b2 = (const float*)d_in[6];
    const float* W3 = (const float*)d_in[7];
    const float* b3 = (const float*)d_in[8];
    float* out = (float*)d_out;

    float* ws      = (float*)d_ws;
    float* E_part  = ws;                                     // 1024*4224 f (17.3 MB)
    float* E32     = E_part + (size_t)K1_BLOCKS * CELLS;     // 32*4224 f (540 KB)
    float* h1_part = E32 + (size_t)K2_GROUPS * CELLS;        // 256*1024 f (1 MB)
    float* h2_part = h1_part + (size_t)K3_BLOCKS * H1;       // 128*512 f (0.25 MB)

    k1_feat_hist<<<K1_BLOCKS, K1_THREADS, 0, stream>>>(x, Wf, bf, E_part);
    k2_reduce<<<dim3(17, K2_GROUPS), 256, 0, stream>>>(E_part, E32);
    k3_h1<<<K3_BLOCKS, 256, 0, stream>>>(E32, W1, h1_part);
    k5_h2<<<128, 128, 0, stream>>>(h1_part, b1, W2, h2_part);
    k6_final<<<1, 512, 0, stream>>>(h2_part, b2, W3, b3, out);
}

// Round 4
// 132.231 us; speedup vs baseline: 1.1516x; 1.1516x over previous
//
#include <hip/hip_runtime.h>
#include <math.h>

#define N_SAMP 16384
#define DIN 128
#define FDIM 128
#define BINS 32
#define NEDGE 33
#define CELLS (FDIM * NEDGE)   // 4224
#define H1 1024
#define H2 512
#define NC 10

#define K1_BLOCKS 1024
#define K1_ROWS 16             // 1024*16 = 16384 samples
#define K1_THREADS 256
#define XSS 132                // fp32 x-tile stride (16B-aligned rows, 2-way banks)
#define WTS 136                // bf16 wfT stride (272B rows: 16B-aligned, 2-way banks)

#define K3_BLOCKS 256
#define EXP_3_125 22.7598950f  // e^3.125

typedef __attribute__((ext_vector_type(8))) short bf16x8;
typedef __attribute__((ext_vector_type(4))) float f32x4;

__device__ __forceinline__ float sig_from_t(float t) {
    // sigma = 1/(1+t), t = e^{-z}; t->0 => 1, t->inf => 0 (exact saturation)
    return __builtin_amdgcn_rcpf(1.f + t);
}
__device__ __forceinline__ float lrelu(float x) { return x > 0.f ? x : 0.01f * x; }
__device__ __forceinline__ unsigned short f2bf(float f) {   // RNE fp32->bf16
    unsigned int u = __float_as_uint(f);
    u += 0x7FFF + ((u >> 16) & 1);
    return (unsigned short)(u >> 16);
}

template <int NE>
__device__ __forceinline__ void sig_chain(float z0neg, float* locE) {
    // t_j = e^{z0neg + 3.125 j}, monotone in j; flush->0 / inf both correct.
    float tt = __expf(z0neg);
    #pragma unroll
    for (int j = 0; j < NE; ++j) {
        locE[j] += sig_from_t(tt);
        tt *= EXP_3_125;
    }
}

// ---------------------------------------------------------------------------
// K0: Wf[128][128] fp32 -> wfT_g[n][k] bf16 packed (row-major in n, 64 dwords
//     per row). One-off 64 KB transform so k1 can stage B coalesced.
// ---------------------------------------------------------------------------
__global__ __launch_bounds__(256) void k0_wfT(
    const float* __restrict__ Wf, unsigned int* __restrict__ wfT_g)
{
    __shared__ unsigned short tile[8 * 128];   // [nj][k]
    const int b = blockIdx.x;                  // 16 blocks, n0 = b*8
    const int t = threadIdx.x;
    const int k = t & 127, half = t >> 7;
    #pragma unroll
    for (int j = 0; j < 4; ++j) {
        const int nj = half * 4 + j;
        tile[nj * 128 + k] = f2bf(Wf[k * FDIM + b * 8 + nj]);
    }
    __syncthreads();
    const unsigned int* tl = (const unsigned int*)tile;
    #pragma unroll
    for (int j = 0; j < 2; ++j) {
        const int d = t + 256 * j;             // 0..511 dwords
        const int nj = d >> 6, kd = d & 63;
        wfT_g[(size_t)(b * 8 + nj) * 64 + kd] = tl[nj * 64 + kd];
    }
}

// ---------------------------------------------------------------------------
// K1: MFMA bf16 feats GEMM + sigmoid + edge-sum histogram.
//     1024 blocks x 256 thr (4 waves) x 16 rows; ~43 KB LDS -> 3 blocks/CU.
// ---------------------------------------------------------------------------
__global__ __launch_bounds__(K1_THREADS, 4) void k1_feat_hist(
    const float* __restrict__ x, const unsigned int* __restrict__ wfT_g,
    const float* __restrict__ bfeat, float* __restrict__ E_part)
{
    __shared__ float xs[K1_ROWS * XSS];            // 8448 B, reused for s
    __shared__ unsigned short wfT[FDIM * WTS];     // 34816 B
    const int t = threadIdx.x, blk = blockIdx.x;
    const int row0 = blk * K1_ROWS;

    // ---- stage x tile: 16 x 128 fp32, float4 coalesced (2 per thread) ----
    {
        int r = t >> 5, c4 = (t & 31) << 2;
        *(float4*)&xs[r * XSS + c4] = *(const float4*)(x + (size_t)(row0 + r) * DIN + c4);
        const int i1 = t + 256;
        r = i1 >> 5; c4 = (i1 & 31) << 2;
        *(float4*)&xs[r * XSS + c4] = *(const float4*)(x + (size_t)(row0 + r) * DIN + c4);
    }
    // ---- stage wfT: 128 rows x 64 dwords, dwordx4 coalesced (8 per thread) ----
    {
        unsigned int* wd = (unsigned int*)wfT;
        #pragma unroll
        for (int j = 0; j < 8; ++j) {
            const int p = t + 256 * j;         // uint4 chunk 0..2047
            const int n = p >> 4, k16 = (p & 15) << 2;
            const uint4 v = *(const uint4*)(wfT_g + (size_t)n * 64 + k16);
            *(uint4*)&wd[n * (WTS / 2) + k16] = v;
        }
    }
    __syncthreads();

    // ---- MFMA: wave w -> feats [w*32, w*32+32); all 16 rows ----
    const int w = t >> 6, L = t & 63;
    const int m = L & 15, q = L >> 4;          // lane row / quad

    bf16x8 afr[4];
    #pragma unroll
    for (int kc = 0; kc < 4; ++kc) {           // A: x[m][kc*32 + q*8 + j]
        const float* ap = &xs[m * XSS + kc * 32 + q * 8];
        const float4 a0 = *(const float4*)ap;
        const float4 a1 = *(const float4*)(ap + 4);
        bf16x8 af;
        af[0] = (short)f2bf(a0.x); af[1] = (short)f2bf(a0.y);
        af[2] = (short)f2bf(a0.z); af[3] = (short)f2bf(a0.w);
        af[4] = (short)f2bf(a1.x); af[5] = (short)f2bf(a1.y);
        af[6] = (short)f2bf(a1.z); af[7] = (short)f2bf(a1.w);
        afr[kc] = af;
    }

    f32x4 acc0 = {0.f, 0.f, 0.f, 0.f}, acc1 = {0.f, 0.f, 0.f, 0.f};
    #pragma unroll
    for (int kc = 0; kc < 4; ++kc) {           // B: wfT[nb+m][kc*32 + q*8 + j]
        const bf16x8 b0 = *(const bf16x8*)&wfT[(w * 32 + m) * WTS + kc * 32 + q * 8];
        const bf16x8 b1 = *(const bf16x8*)&wfT[(w * 32 + 16 + m) * WTS + kc * 32 + q * 8];
        acc0 = __builtin_amdgcn_mfma_f32_16x16x32_bf16(afr[kc], b0, acc0, 0, 0, 0);
        acc1 = __builtin_amdgcn_mfma_f32_16x16x32_bf16(afr[kc], b1, acc1, 0, 0, 0);
    }

    __syncthreads();   // all A/B LDS reads done before s overwrites xs

    // ---- sigmoid epilogue in C-layout: col=m (feat), row=q*4+reg ----
    {
        const int f0 = w * 32 + m;
        const float bias0 = bfeat[f0], bias1 = bfeat[f0 + 16];
        #pragma unroll
        for (int r = 0; r < 4; ++r) {
            const int row = q * 4 + r;
            xs[row * XSS + f0]      = sig_from_t(__expf(-(acc0[r] + bias0)));
            xs[row * XSS + f0 + 16] = sig_from_t(__expf(-(acc1[r] + bias1)));
        }
    }
    __syncthreads();

    // ---- edge sums: thread = (feat, half); chains of 17 / 16 edges ----
    const int feat = t & 127;
    const int eg = t >> 7;                     // wave-uniform (waves 0,1 vs 2,3)
    const int estart = eg ? 17 : 0;
    const int ne = eg ? 16 : 17;
    const float c0 = 3.125f * (float)estart;

    float locE[17];
    #pragma unroll
    for (int j = 0; j < 17; ++j) locE[j] = 0.f;

    for (int r = 0; r < K1_ROWS; ++r) {
        const float z100 = 100.f * xs[r * XSS + feat];
        if (eg == 0) sig_chain<17>(c0 - z100, locE);
        else         sig_chain<16>(c0 - z100, locE);
    }

    float* dst = E_part + (size_t)blk * CELLS + feat * NEDGE + estart;
    for (int j = 0; j < ne; ++j) dst[j] = locE[j];
}

// ---------------------------------------------------------------------------
// K2: coalesced reduce E_part[1024][4224] -> E32[32][4224]
// ---------------------------------------------------------------------------
__global__ __launch_bounds__(256) void k2_reduce(
    const float* __restrict__ E_part, float* __restrict__ E32)
{
    const int cell = blockIdx.x * 256 + threadIdx.x;
    if (cell >= CELLS) return;
    const int g = blockIdx.y;
    const float* p = E_part + (size_t)g * 32 * CELLS + cell;
    float a0 = 0, a1 = 0, a2 = 0, a3 = 0;
    #pragma unroll
    for (int q = 0; q < 32; q += 4) {
        a0 += p[(size_t)(q + 0) * CELLS];
        a1 += p[(size_t)(q + 1) * CELLS];
        a2 += p[(size_t)(q + 2) * CELLS];
        a3 += p[(size_t)(q + 3) * CELLS];
    }
    E32[g * CELLS + cell] = (a0 + a1) + (a2 + a3);
}

// ---------------------------------------------------------------------------
// K3: final 32-way reduce of 17 edges (L2-hot), telescope to 16 hist vals,
//     then h1_part[b][:] = hist-chunk @ 16 W1 rows (register-prefetched).
// ---------------------------------------------------------------------------
__global__ __launch_bounds__(256) void k3_h1(
    const float* __restrict__ E32, const float* __restrict__ W1,
    float* __restrict__ h1_part)
{
    const int b = blockIdx.x, t = threadIdx.x;
    const int f = b >> 1, bin0 = (b & 1) * 16;
    const int c0 = f * NEDGE + bin0;

    float4 w[16];
    #pragma unroll
    for (int k = 0; k < 16; ++k)
        w[k] = *(const float4*)(W1 + (size_t)(b * 16 + k) * H1 + t * 4);

    __shared__ float hl[17];
    if (t < 17) {
        const float* p = E32 + c0 + t;
        float a0 = 0, a1 = 0, a2 = 0, a3 = 0;
        #pragma unroll
        for (int g = 0; g < 32; g += 4) {
            a0 += p[(size_t)(g + 0) * CELLS];
            a1 += p[(size_t)(g + 1) * CELLS];
            a2 += p[(size_t)(g + 2) * CELLS];
            a3 += p[(size_t)(g + 3) * CELLS];
        }
        hl[t] = (a0 + a1) + (a2 + a3);
    }
    __syncthreads();

    float4 acc = {0, 0, 0, 0};
    #pragma unroll
    for (int k = 0; k < 16; ++k) {
        const float h = (hl[k] - hl[k + 1]) * (1.f / (float)N_SAMP);
        acc.x = fmaf(h, w[k].x, acc.x);
        acc.y = fmaf(h, w[k].y, acc.y);
        acc.z = fmaf(h, w[k].z, acc.z);
        acc.w = fmaf(h, w[k].w, acc.w);
    }
    *(float4*)(h1_part + (size_t)b * H1 + t * 4) = acc;
}

// ---------------------------------------------------------------------------
// K5: finalize 8 h1 entries (256-way reduce + b1 + leaky), then
//     h2_part[b][:] = h1-chunk @ 8 W2 rows (register-prefetched).
// ---------------------------------------------------------------------------
__global__ __launch_bounds__(128) void k5_h2(
    const float* __restrict__ h1_part, const float* __restrict__ b1,
    const float* __restrict__ W2, float* __restrict__ h2_part)
{
    const int b = blockIdx.x, t = threadIdx.x;   // 128 blocks x 128 thr

    float4 w[8];
    #pragma unroll
    for (int k = 0; k < 8; ++k)
        w[k] = *(const float4*)(W2 + (size_t)(b * 8 + k) * H2 + t * 4);

    __shared__ float hred[8 * 16];
    __shared__ float hv[8];
    const int col = t & 7, q = t >> 3;
    {
        const float* p0 = h1_part + (size_t)(q * 16) * H1 + b * 8 + col;
        float a0 = 0, a1 = 0, a2 = 0, a3 = 0;
        #pragma unroll
        for (int p = 0; p < 16; p += 4) {
            a0 += p0[(size_t)(p + 0) * H1];
            a1 += p0[(size_t)(p + 1) * H1];
            a2 += p0[(size_t)(p + 2) * H1];
            a3 += p0[(size_t)(p + 3) * H1];
        }
        hred[col * 16 + q] = (a0 + a1) + (a2 + a3);
    }
    __syncthreads();
    if (t < 8) {
        float s = 0.f;
        #pragma unroll
        for (int q2 = 0; q2 < 16; ++q2) s += hred[t * 16 + q2];
        hv[t] = lrelu(s + b1[b * 8 + t]);
    }
    __syncthreads();

    float4 acc = {0, 0, 0, 0};
    #pragma unroll
    for (int k = 0; k < 8; ++k) {
        const float h = hv[k];
        acc.x = fmaf(h, w[k].x, acc.x);
        acc.y = fmaf(h, w[k].y, acc.y);
        acc.z = fmaf(h, w[k].z, acc.z);
        acc.w = fmaf(h, w[k].w, acc.w);
    }
    *(float4*)(h2_part + (size_t)b * H2 + t * 4) = acc;
}

// ---------------------------------------------------------------------------
// K6: finalize h2 (128-way reduce + b2 + leaky), logits = h2@W3 + b3,
//     softmax -> out[10]. Single block of 512.
// ---------------------------------------------------------------------------
__global__ __launch_bounds__(512) void k6_final(
    const float* __restrict__ h2_part, const float* __restrict__ b2,
    const float* __restrict__ W3, const float* __restrict__ b3,
    float* __restrict__ out)
{
    const int t = threadIdx.x;
    float a0 = 0, a1 = 0, a2 = 0, a3 = 0;
    #pragma unroll 8
    for (int p = 0; p < 128; p += 4) {
        a0 += h2_part[(size_t)(p + 0) * H2 + t];
        a1 += h2_part[(size_t)(p + 1) * H2 + t];
        a2 += h2_part[(size_t)(p + 2) * H2 + t];
        a3 += h2_part[(size_t)(p + 3) * H2 + t];
    }
    const float h2v = lrelu(((a0 + a1) + (a2 + a3)) + b2[t]);

    float lc[NC];
    #pragma unroll
    for (int c = 0; c < NC; ++c) lc[c] = h2v * W3[t * NC + c];
    #pragma unroll
    for (int off = 32; off >= 1; off >>= 1) {
        #pragma unroll
        for (int c = 0; c < NC; ++c) lc[c] += __shfl_down(lc[c], off, 64);
    }

    __shared__ float wsum[8][NC];
    if ((t & 63) == 0) {
        #pragma unroll
        for (int c = 0; c < NC; ++c) wsum[t >> 6][c] = lc[c];
    }
    __syncthreads();

    if (t == 0) {
        float logits[NC];
        float m = -1e30f;
        #pragma unroll
        for (int c = 0; c < NC; ++c) {
            float v = b3[c];
            for (int ww = 0; ww < 8; ++ww) v += wsum[ww][c];
            logits[c] = v;
            m = fmaxf(m, v);
        }
        float ssum = 0.f;
        #pragma unroll
        for (int c = 0; c < NC; ++c) { logits[c] = __expf(logits[c] - m); ssum += logits[c]; }
        const float inv = 1.f / ssum;
        #pragma unroll
        for (int c = 0; c < NC; ++c) out[c] = logits[c] * inv;
    }
}

extern "C" void kernel_launch(void* const* d_in, const int* in_sizes, int n_in,
                              void* d_out, int out_size, void* d_ws, size_t ws_size,
                              hipStream_t stream)
{
    const float* x  = (const float*)d_in[0];
    const float* Wf = (const float*)d_in[1];
    const float* bf = (const float*)d_in[2];
    const float* W1 = (const float*)d_in[3];
    const float* b1 = (const float*)d_in[4];
    const float* W2 = (const float*)d_in[5];
    const float* b2 = (const float*)d_in[6];
    const float* W3 = (const float*)d_in[7];
    const float* b3 = (const float*)d_in[8];
    float* out = (float*)d_out;

    float* ws      = (float*)d_ws;
    float* E_part  = ws;                                     // 1024*4224 f (17.3 MB)
    float* E32     = E_part + (size_t)K1_BLOCKS * CELLS;     // 32*4224 f
    float* h1_part = E32 + (size_t)32 * CELLS;               // 256*1024 f
    float* h2_part = h1_part + (size_t)K3_BLOCKS * H1;       // 128*512 f
    unsigned int* wfT_g = (unsigned int*)(h2_part + 128 * H2); // 8192 dwords (32 KB)

    k0_wfT<<<16, 256, 0, stream>>>(Wf, wfT_g);
    k1_feat_hist<<<K1_BLOCKS, K1_THREADS, 0, stream>>>(x, wfT_g, bf, E_part);
    k2_reduce<<<dim3(17, 32), 256, 0, stream>>>(E_part, E32);
    k3_h1<<<K3_BLOCKS, 256, 0, stream>>>(E32, W1, h1_part);
    k5_h2<<<128, 128, 0, stream>>>(h1_part, b1, W2, h2_part);
    k6_final<<<1, 512, 0, stream>>>(h2_part, b2, W3, b3, out);
}

// Round 5
// 115.013 us; speedup vs baseline: 1.3240x; 1.1497x over previous
//
#include <hip/hip_runtime.h>
#include <math.h>

#define N_SAMP 16384
#define DIN 128
#define FDIM 128
#define BINS 32
#define NEDGE 33
#define CELLS (FDIM * NEDGE)   // 4224
#define H1 1024
#define H2 512
#define NC 10

#define K1_BLOCKS 512
#define K1_ROWS 32             // 512*32 = 16384 samples
#define K1_THREADS 256
#define XBS 136                // bf16 x-tile stride (shorts): 272B rows, 16B-aligned
#define SSS 132                // fp32 s-tile stride (floats): 2-way banks (free)

#define K3_BLOCKS 256
#define EXP_3_125 22.7598950f  // e^3.125

typedef __attribute__((ext_vector_type(8))) short bf16x8;
typedef __attribute__((ext_vector_type(4))) float f32x4;

__device__ __forceinline__ float sig_from_t(float t) {
    // sigma = 1/(1+t), t = e^{-z}; t->0 => 1, t->inf => 0 (exact saturation)
    return __builtin_amdgcn_rcpf(1.f + t);
}
__device__ __forceinline__ float lrelu(float x) { return x > 0.f ? x : 0.01f * x; }
__device__ __forceinline__ unsigned short f2bf(float f) {   // RNE fp32->bf16
    unsigned int u = __float_as_uint(f);
    u += 0x7FFF + ((u >> 16) & 1);
    return (unsigned short)(u >> 16);
}

template <int NE>
__device__ __forceinline__ void sig_chain(float z0neg, float* locE) {
    // t_j = e^{z0neg + 3.125 j}, monotone in j; flush->0 / inf both correct.
    float tt = __expf(z0neg);
    #pragma unroll
    for (int j = 0; j < NE; ++j) {
        locE[j] += sig_from_t(tt);
        tt *= EXP_3_125;
    }
}

// ---------------------------------------------------------------------------
// K0: Wf[128][128] fp32 -> wfT_g[n][k] bf16 packed (64 dwords per n-row).
// ---------------------------------------------------------------------------
__global__ __launch_bounds__(256) void k0_wfT(
    const float* __restrict__ Wf, unsigned int* __restrict__ wfT_g)
{
    __shared__ unsigned short tile[8 * 128];   // [nj][k]
    const int b = blockIdx.x;                  // 16 blocks, n0 = b*8
    const int t = threadIdx.x;
    const int k = t & 127, half = t >> 7;
    #pragma unroll
    for (int j = 0; j < 4; ++j) {
        const int nj = half * 4 + j;
        tile[nj * 128 + k] = f2bf(Wf[k * FDIM + b * 8 + nj]);
    }
    __syncthreads();
    const unsigned int* tl = (const unsigned int*)tile;
    #pragma unroll
    for (int j = 0; j < 2; ++j) {
        const int d = t + 256 * j;             // 0..511 dwords
        const int nj = d >> 6, kd = d & 63;
        wfT_g[(size_t)(b * 8 + nj) * 64 + kd] = tl[nj * 64 + kd];
    }
}

// ---------------------------------------------------------------------------
// K1: MFMA bf16 feats GEMM + sigmoid + edge-sum histogram.
//     512 blocks x 256 thr (4 waves) x 32 rows. LDS 25.6 KB.
//     B fragments straight from L2-resident wfT_g (no LDS staging).
//     E_part layout [blk][edge][feat] -> coalesced dword stores (lane=feat).
// ---------------------------------------------------------------------------
__global__ __launch_bounds__(K1_THREADS, 3) void k1_feat_hist(
    const float* __restrict__ x, const unsigned int* __restrict__ wfT_g,
    const float* __restrict__ bfeat, float* __restrict__ E_part)
{
    __shared__ unsigned short xbf[K1_ROWS * XBS];   // 8704 B (bf16 x tile)
    __shared__ float s[K1_ROWS * SSS];              // 16896 B (sigmoid outputs)
    const int t = threadIdx.x, blk = blockIdx.x;
    const int w = t >> 6, L = t & 63;
    const int m = L & 15, q = L >> 4;               // MFMA lane row / quad

    // ---- B fragments from global: wave w owns feats [w*32, w*32+32) ----
    // B[n][k]: n = lane&15 (+16 for fh=1), k = q*8+j within kc-chunk of 32.
    bf16x8 bfrag[2][4];
    #pragma unroll
    for (int fh = 0; fh < 2; ++fh) {
        const int n = w * 32 + fh * 16 + m;
        #pragma unroll
        for (int kc = 0; kc < 4; ++kc)
            bfrag[fh][kc] = *(const bf16x8*)(wfT_g + (size_t)n * 64 + kc * 16 + q * 4);
    }

    // ---- stage x tile as bf16: 32 rows x 128 cols (4 float4 per thread) ----
    const int row0 = blk * K1_ROWS;
    #pragma unroll
    for (int i = 0; i < 4; ++i) {
        const int idx = t + i * 256;
        const int r = idx >> 5, c4 = (idx & 31) << 2;
        const float4 v = *(const float4*)(x + (size_t)(row0 + r) * DIN + c4);
        unsigned short* p = &xbf[r * XBS + c4];
        p[0] = f2bf(v.x); p[1] = f2bf(v.y); p[2] = f2bf(v.z); p[3] = f2bf(v.w);
    }
    __syncthreads();

    // ---- MFMA: 2 row-tiles x 2 feat-halves x 4 k-chunks ----
    f32x4 acc[2][2];
    #pragma unroll
    for (int rt = 0; rt < 2; ++rt)
        #pragma unroll
        for (int fh = 0; fh < 2; ++fh)
            acc[rt][fh] = (f32x4){0.f, 0.f, 0.f, 0.f};

    #pragma unroll
    for (int kc = 0; kc < 4; ++kc) {
        const bf16x8 a0 = *(const bf16x8*)&xbf[m * XBS + kc * 32 + q * 8];
        const bf16x8 a1 = *(const bf16x8*)&xbf[(16 + m) * XBS + kc * 32 + q * 8];
        acc[0][0] = __builtin_amdgcn_mfma_f32_16x16x32_bf16(a0, bfrag[0][kc], acc[0][0], 0, 0, 0);
        acc[0][1] = __builtin_amdgcn_mfma_f32_16x16x32_bf16(a0, bfrag[1][kc], acc[0][1], 0, 0, 0);
        acc[1][0] = __builtin_amdgcn_mfma_f32_16x16x32_bf16(a1, bfrag[0][kc], acc[1][0], 0, 0, 0);
        acc[1][1] = __builtin_amdgcn_mfma_f32_16x16x32_bf16(a1, bfrag[1][kc], acc[1][1], 0, 0, 0);
    }

    // ---- sigmoid epilogue in C-layout: col = m (feat), row = q*4 + reg ----
    {
        const int f0 = w * 32 + m;
        const float b0v = bfeat[f0], b1v = bfeat[f0 + 16];
        #pragma unroll
        for (int rt = 0; rt < 2; ++rt)
            #pragma unroll
            for (int r = 0; r < 4; ++r) {
                const int row = rt * 16 + q * 4 + r;
                s[row * SSS + f0]      = sig_from_t(__expf(-(acc[rt][0][r] + b0v)));
                s[row * SSS + f0 + 16] = sig_from_t(__expf(-(acc[rt][1][r] + b1v)));
            }
    }
    __syncthreads();

    // ---- edge sums: thread = (feat, half); chains of 17 / 16 edges ----
    const int feat = t & 127;
    const int eg = t >> 7;                     // wave-uniform
    const int estart = eg ? 17 : 0;
    const int ne = eg ? 16 : 17;
    const float c0 = 3.125f * (float)estart;

    float locE[17];
    #pragma unroll
    for (int j = 0; j < 17; ++j) locE[j] = 0.f;

    for (int r = 0; r < K1_ROWS; ++r) {
        const float z0neg = c0 - 100.f * s[r * SSS + feat];
        if (eg == 0) sig_chain<17>(z0neg, locE);
        else         sig_chain<16>(z0neg, locE);
    }

    // coalesced: lane = feat, contiguous 256B per wave-store
    float* dst = E_part + (size_t)blk * CELLS + estart * FDIM + feat;
    for (int j = 0; j < ne; ++j) dst[j * FDIM] = locE[j];
}

// ---------------------------------------------------------------------------
// K2: coalesced reduce E_part[512][4224] -> E32[32][4224]  (16 partials each)
// ---------------------------------------------------------------------------
__global__ __launch_bounds__(256) void k2_reduce(
    const float* __restrict__ E_part, float* __restrict__ E32)
{
    const int cell = blockIdx.x * 256 + threadIdx.x;
    if (cell >= CELLS) return;
    const int g = blockIdx.y;
    const float* p = E_part + (size_t)g * 16 * CELLS + cell;
    float a0 = 0, a1 = 0, a2 = 0, a3 = 0;
    #pragma unroll
    for (int qq = 0; qq < 16; qq += 4) {
        a0 += p[(size_t)(qq + 0) * CELLS];
        a1 += p[(size_t)(qq + 1) * CELLS];
        a2 += p[(size_t)(qq + 2) * CELLS];
        a3 += p[(size_t)(qq + 3) * CELLS];
    }
    E32[g * CELLS + cell] = (a0 + a1) + (a2 + a3);
}

// ---------------------------------------------------------------------------
// K3: final 32-way reduce of 17 edges (L2-hot E32, [edge][feat] layout),
//     telescope to 16 hist vals, then h1_part[b][:] = hist-chunk @ 16 W1 rows
//     (register-prefetched to hide the HBM stream behind the reduce).
// ---------------------------------------------------------------------------
__global__ __launch_bounds__(256) void k3_h1(
    const float* __restrict__ E32, const float* __restrict__ W1,
    float* __restrict__ h1_part)
{
    const int b = blockIdx.x, t = threadIdx.x;
    const int f = b >> 1, bin0 = (b & 1) * 16;

    float4 wr[16];
    #pragma unroll
    for (int k = 0; k < 16; ++k)
        wr[k] = *(const float4*)(W1 + (size_t)(b * 16 + k) * H1 + t * 4);

    __shared__ float hl[17];
    if (t < 17) {
        const float* p = E32 + (bin0 + t) * FDIM + f;
        float a0 = 0, a1 = 0, a2 = 0, a3 = 0;
        #pragma unroll
        for (int g = 0; g < 32; g += 4) {
            a0 += p[(size_t)(g + 0) * CELLS];
            a1 += p[(size_t)(g + 1) * CELLS];
            a2 += p[(size_t)(g + 2) * CELLS];
            a3 += p[(size_t)(g + 3) * CELLS];
        }
        hl[t] = (a0 + a1) + (a2 + a3);
    }
    __syncthreads();

    float4 acc = {0, 0, 0, 0};
    #pragma unroll
    for (int k = 0; k < 16; ++k) {
        const float h = (hl[k] - hl[k + 1]) * (1.f / (float)N_SAMP);
        acc.x = fmaf(h, wr[k].x, acc.x);
        acc.y = fmaf(h, wr[k].y, acc.y);
        acc.z = fmaf(h, wr[k].z, acc.z);
        acc.w = fmaf(h, wr[k].w, acc.w);
    }
    *(float4*)(h1_part + (size_t)b * H1 + t * 4) = acc;
}

// ---------------------------------------------------------------------------
// K5: finalize 16 h1 entries (256-way reduce + b1 + leaky), then
//     h2_part[b][:] = h1-chunk @ 16 W2 rows (register-prefetched).
//     64 blocks x 128 thr -> k6 only reduces 64 partials.
// ---------------------------------------------------------------------------
__global__ __launch_bounds__(128) void k5_h2(
    const float* __restrict__ h1_part, const float* __restrict__ b1,
    const float* __restrict__ W2, float* __restrict__ h2_part)
{
    const int b = blockIdx.x, t = threadIdx.x;

    float4 wr[16];
    #pragma unroll
    for (int k = 0; k < 16; ++k)
        wr[k] = *(const float4*)(W2 + (size_t)(b * 16 + k) * H2 + t * 4);

    __shared__ float hred[16 * 8];
    __shared__ float hv[16];
    const int c = t & 15, qg = t >> 4;   // 8 partial-groups of 32
    {
        const float* p0 = h1_part + (size_t)(qg * 32) * H1 + b * 16 + c;
        float a0 = 0, a1 = 0, a2 = 0, a3 = 0;
        #pragma unroll
        for (int p = 0; p < 32; p += 4) {
            a0 += p0[(size_t)(p + 0) * H1];
            a1 += p0[(size_t)(p + 1) * H1];
            a2 += p0[(size_t)(p + 2) * H1];
            a3 += p0[(size_t)(p + 3) * H1];
        }
        hred[c * 8 + qg] = (a0 + a1) + (a2 + a3);
    }
    __syncthreads();
    if (t < 16) {
        float sum = 0.f;
        #pragma unroll
        for (int g = 0; g < 8; ++g) sum += hred[t * 8 + g];
        hv[t] = lrelu(sum + b1[b * 16 + t]);
    }
    __syncthreads();

    float4 acc = {0, 0, 0, 0};
    #pragma unroll
    for (int k = 0; k < 16; ++k) {
        const float h = hv[k];
        acc.x = fmaf(h, wr[k].x, acc.x);
        acc.y = fmaf(h, wr[k].y, acc.y);
        acc.z = fmaf(h, wr[k].z, acc.z);
        acc.w = fmaf(h, wr[k].w, acc.w);
    }
    *(float4*)(h2_part + (size_t)b * H2 + t * 4) = acc;
}

// ---------------------------------------------------------------------------
// K6: finalize h2 (64-way reduce + b2 + leaky), logits = h2@W3 + b3,
//     softmax -> out[10]. Single block of 512.
// ---------------------------------------------------------------------------
__global__ __launch_bounds__(512) void k6_final(
    const float* __restrict__ h2_part, const float* __restrict__ b2,
    const float* __restrict__ W3, const float* __restrict__ b3,
    float* __restrict__ out)
{
    const int t = threadIdx.x;
    float a0 = 0, a1 = 0, a2 = 0, a3 = 0;
    #pragma unroll
    for (int p = 0; p < 64; p += 4) {
        a0 += h2_part[(size_t)(p + 0) * H2 + t];
        a1 += h2_part[(size_t)(p + 1) * H2 + t];
        a2 += h2_part[(size_t)(p + 2) * H2 + t];
        a3 += h2_part[(size_t)(p + 3) * H2 + t];
    }
    const float h2v = lrelu(((a0 + a1) + (a2 + a3)) + b2[t]);

    float lc[NC];
    #pragma unroll
    for (int c = 0; c < NC; ++c) lc[c] = h2v * W3[t * NC + c];
    #pragma unroll
    for (int off = 32; off >= 1; off >>= 1) {
        #pragma unroll
        for (int c = 0; c < NC; ++c) lc[c] += __shfl_down(lc[c], off, 64);
    }

    __shared__ float wsum[8][NC];
    if ((t & 63) == 0) {
        #pragma unroll
        for (int c = 0; c < NC; ++c) wsum[t >> 6][c] = lc[c];
    }
    __syncthreads();

    if (t == 0) {
        float logits[NC];
        float mx = -1e30f;
        #pragma unroll
        for (int c = 0; c < NC; ++c) {
            float v = b3[c];
            for (int ww = 0; ww < 8; ++ww) v += wsum[ww][c];
            logits[c] = v;
            mx = fmaxf(mx, v);
        }
        float ssum = 0.f;
        #pragma unroll
        for (int c = 0; c < NC; ++c) { logits[c] = __expf(logits[c] - mx); ssum += logits[c]; }
        const float inv = 1.f / ssum;
        #pragma unroll
        for (int c = 0; c < NC; ++c) out[c] = logits[c] * inv;
    }
}

extern "C" void kernel_launch(void* const* d_in, const int* in_sizes, int n_in,
                              void* d_out, int out_size, void* d_ws, size_t ws_size,
                              hipStream_t stream)
{
    const float* x  = (const float*)d_in[0];
    const float* Wf = (const float*)d_in[1];
    const float* bf = (const float*)d_in[2];
    const float* W1 = (const float*)d_in[3];
    const float* b1 = (const float*)d_in[4];
    const float* W2 = (const float*)d_in[5];
    const float* b2 = (const float*)d_in[6];
    const float* W3 = (const float*)d_in[7];
    const float* b3 = (const float*)d_in[8];
    float* out = (float*)d_out;

    float* ws      = (float*)d_ws;
    float* E_part  = ws;                                     // 512*4224 f (8.65 MB)
    float* E32     = E_part + (size_t)K1_BLOCKS * CELLS;     // 32*4224 f
    float* h1_part = E32 + (size_t)32 * CELLS;               // 256*1024 f
    float* h2_part = h1_part + (size_t)K3_BLOCKS * H1;       // 64*512 f
    unsigned int* wfT_g = (unsigned int*)(h2_part + 64 * H2); // 8192 dwords (32 KB)

    k0_wfT<<<16, 256, 0, stream>>>(Wf, wfT_g);
    k1_feat_hist<<<K1_BLOCKS, K1_THREADS, 0, stream>>>(x, wfT_g, bf, E_part);
    k2_reduce<<<dim3(17, 32), 256, 0, stream>>>(E_part, E32);
    k3_h1<<<K3_BLOCKS, 256, 0, stream>>>(E32, W1, h1_part);
    k5_h2<<<64, 128, 0, stream>>>(h1_part, b1, W2, h2_part);
    k6_final<<<1, 512, 0, stream>>>(h2_part, b2, W3, b3, out);
}